// Round 2
// baseline (137.599 us; speedup 1.0000x reference)
//
#include <hip/hip_runtime.h>
#include <math.h>

#define IMG 256
#define NPIX (IMG*IMG)
#define SIGMA_INV 100.0f
#define EPSF 1e-6f
#define LOG2E 1.4426950408889634f
#define TANV 0.5773502691896258f   // tan(30 deg)
#define TSKIP 24.0f
#define MAXCHUNK 8

__device__ __forceinline__ float fexp2(float x) { return exp2f(x); }
__device__ __forceinline__ float frcp(float x) { return __frcp_rn(x); }

// Fused prep: project each face's 3 vertices (camera math recomputed per
// thread -- trivial) and emit 3 edge-constant float4s per face.
// t_k(p) = px*A.x + py*A.y + A.z ; frag = 1/((1+2^t0)(1+2^t1)(1+2^t2))
__global__ void prep_kernel(const float* __restrict__ verts,
                            const int* __restrict__ faces,
                            const float* __restrict__ cam,
                            float4* __restrict__ fd, int F) {
  int f = blockIdx.x * blockDim.x + threadIdx.x;
  if (f >= F) return;
  float ex = cam[0], ey = cam[1], ez = cam[2];
  float zn = sqrtf(ex * ex + ey * ey + ez * ez) + EPSF;
  float zx = -ex / zn, zy = -ey / zn, zz = -ez / zn;
  float xn = sqrtf(zz * zz + zx * zx) + EPSF;
  float xx = zz / xn, xy = 0.0f, xz = -zx / xn;
  float yx = zy * xz - zz * xy;
  float yy = zz * xx - zx * xz;
  float yz = zx * xy - zy * xx;

  float pxs[3], pys[3];
#pragma unroll
  for (int k = 0; k < 3; ++k) {
    int vi = faces[3 * f + k];
    float px = verts[3 * vi + 0] - ex;
    float py = verts[3 * vi + 1] - ey;
    float pz = verts[3 * vi + 2] - ez;
    float vx = px * xx + py * xy + pz * xz;
    float vy = px * yx + py * yy + pz * yz;
    float vz = px * zx + py * zy + pz * zz;
    float zw = vz * TANV;
    pxs[k] = vx / zw;
    pys[k] = vy / zw;
  }
  float e01x = pxs[1] - pxs[0], e01y = pys[1] - pys[0];
  float e02x = pxs[2] - pxs[0], e02y = pys[2] - pys[0];
  float area = e01x * e02y - e01y * e02x;
  float s = (area > 0.0f) ? 1.0f : ((area < 0.0f) ? -1.0f : 0.0f);
  float K = -s * SIGMA_INV * LOG2E;
#pragma unroll
  for (int k = 0; k < 3; ++k) {
    int kn = (k == 2) ? 0 : k + 1;
    float dx = pxs[kn] - pxs[k], dy = pys[kn] - pys[k];
    float ln = sqrtf(dx * dx + dy * dy) + EPSF;
    float nx = -dy / ln, ny = dx / ln;
    float c = pxs[k] * nx + pys[k] * ny;
    fd[f * 3 + k] = make_float4(nx * K, ny * K, -c * K, 0.0f);
  }
}

// Silhouette partial product. Each wave owns one 8x8 pixel tile for one
// face chunk. Phase 1 (lane-parallel): lane j tests face base+j against the
// whole tile via the linear bound  min_tile t_k = t_k(center)-(|Ax|+|Ay|)*h;
// face skippable iff some edge has min_tile t_k >= TSKIP (frag <= 2^-24).
// Phase 2 (uniform bit-loop over ballot mask): exp work on relevant faces.
__global__ __launch_bounds__(256) void sil_kernel(const float4* __restrict__ fd,
                                                  float* __restrict__ part,
                                                  int fpc, int F) {
  int tid = threadIdx.x;
  int lane = tid & 63, wave = tid >> 6;
  int tile = blockIdx.x * 4 + wave;           // 0..1023, 32x32 tiles of 8x8
  int ix0 = (tile & 31) << 3;
  int iy0 = (tile >> 5) << 3;
  int ix = ix0 + (lane & 7);
  int iy = iy0 + (lane >> 3);
  float px = (2.0f * (float)ix + 1.0f) * (1.0f / IMG) - 1.0f;
  float py = 1.0f - (2.0f * (float)iy + 1.0f) * (1.0f / IMG);
  float cx = ((float)(2 * ix0 + 8)) * (1.0f / IMG) - 1.0f;
  float cy = 1.0f - ((float)(2 * iy0 + 8)) * (1.0f / IMG);
  const float h = 7.0f / IMG;                 // tile half-extent in NDC

  int f0 = blockIdx.y * fpc;
  int f1 = f0 + fpc; if (f1 > F) f1 = F;

  float acc = 1.0f;
  for (int base = f0; base < f1; base += 64) {
    int f = base + lane;
    int fc = f < F ? f : F - 1;               // clamped for safe load
    float4 a0 = fd[3 * fc + 0];
    float4 a1 = fd[3 * fc + 1];
    float4 a2 = fd[3 * fc + 2];
    float m0 = fmaf(cx, a0.x, fmaf(cy, a0.y, a0.z)) - (fabsf(a0.x) + fabsf(a0.y)) * h;
    float m1 = fmaf(cx, a1.x, fmaf(cy, a1.y, a1.z)) - (fabsf(a1.x) + fabsf(a1.y)) * h;
    float m2 = fmaf(cx, a2.x, fmaf(cy, a2.y, a2.z)) - (fabsf(a2.x) + fabsf(a2.y)) * h;
    bool relevant = (f < f1) && (fmaxf(m0, fmaxf(m1, m2)) < TSKIP);
    unsigned long long mask = __ballot(relevant ? 1 : 0);
    while (mask) {
      int j = __builtin_ctzll(mask);
      mask &= mask - 1;
      int g = base + j;
      float4 b0 = fd[3 * g + 0];
      float4 b1 = fd[3 * g + 1];
      float4 b2 = fd[3 * g + 2];
      float t0 = fmaf(px, b0.x, fmaf(py, b0.y, b0.z));
      float t1 = fmaf(px, b1.x, fmaf(py, b1.y, b1.z));
      float t2 = fmaf(px, b2.x, fmaf(py, b2.y, b2.z));
      float D = (1.0f + fexp2(t0)) * (1.0f + fexp2(t1)) * (1.0f + fexp2(t2));
      acc *= 1.0f - frcp(D);
    }
  }
  part[blockIdx.y * NPIX + iy * IMG + ix] = acc;
}

// Combine chunk partials, squared error vs image_ref, reduce to scalar.
__global__ __launch_bounds__(256) void loss_kernel(const float* __restrict__ part,
                                                   const float* __restrict__ ref,
                                                   float* __restrict__ out,
                                                   int nchunk) {
  int p = blockIdx.x * 256 + threadIdx.x;
  float a = 1.0f;
  for (int c = 0; c < nchunk; ++c) a *= part[c * NPIX + p];
  float d = (1.0f - a) - ref[p];
  float v = d * d;
#pragma unroll
  for (int off = 32; off > 0; off >>= 1) v += __shfl_down(v, off);
  __shared__ float red[4];
  if ((threadIdx.x & 63) == 0) red[threadIdx.x >> 6] = v;
  __syncthreads();
  if (threadIdx.x == 0) atomicAdd(out, red[0] + red[1] + red[2] + red[3]);
}

extern "C" void kernel_launch(void* const* d_in, const int* in_sizes, int n_in,
                              void* d_out, int out_size, void* d_ws, size_t ws_size,
                              hipStream_t stream) {
  const float* verts = (const float*)d_in[0];
  const int* faces = (const int*)d_in[1];
  const float* cam = (const float*)d_in[2];
  const float* imref = (const float*)d_in[3];
  int V = in_sizes[0] / 3;  (void)V;
  int F = in_sizes[1] / 3;  // 1000

  char* ws = (char*)d_ws;
  float4* fd = (float4*)ws;                 // F*3 float4 (48 KB)
  float* part = (float*)(ws + 65536);       // nchunk * NPIX floats
  float* out = (float*)d_out;

  long avail = (long)ws_size - 65536;
  int nchunk = (int)(avail / (long)(NPIX * sizeof(float)));
  if (nchunk > MAXCHUNK) nchunk = MAXCHUNK;
  if (nchunk < 1) nchunk = 1;

  hipMemsetAsync(out, 0, sizeof(float), stream);
  prep_kernel<<<(F + 255) / 256, 256, 0, stream>>>(verts, faces, cam, fd, F);
  int fpc = (F + nchunk - 1) / nchunk;
  dim3 grid(256, nchunk);
  sil_kernel<<<grid, 256, 0, stream>>>(fd, part, fpc, F);
  loss_kernel<<<NPIX / 256, 256, 0, stream>>>(part, imref, out, nchunk);
}

// Round 4
// 104.825 us; speedup vs baseline: 1.3127x; 1.3127x over previous
//
#include <hip/hip_runtime.h>
#include <math.h>

#define IMG 256
#define NPIX (IMG*IMG)
#define SIGMA_INV 100.0f
#define EPSF 1e-6f
#define LOG2E 1.4426950408889634f
#define TANV 0.5773502691896258f   // tan(30 deg)
#define TSKIP 24.0f
#define VMAX 512                   // V = 502
#define FMAX 1024                  // F = 1000
#define NWAVE 8
#define NBLK (NPIX/64)             // 1024 blocks, one 8x8 tile each

__device__ __forceinline__ float fexp2(float x) {
#if __has_builtin(__builtin_amdgcn_exp2f)
  return __builtin_amdgcn_exp2f(x);
#else
  return exp2f(x);
#endif
}
__device__ __forceinline__ float frcp(float x) {
#if __has_builtin(__builtin_amdgcn_rcpf)
  return __builtin_amdgcn_rcpf(x);
#else
  return 1.0f / x;
#endif
}
__device__ __forceinline__ float rlane(float x, int j) {
#if __has_builtin(__builtin_amdgcn_readlane)
  return __int_as_float(__builtin_amdgcn_readlane(__float_as_int(x), j));
#else
  return __shfl(x, j);
#endif
}

// Cross product WITHOUT fma contraction. sign(area) is discontinuous:
// faces with a repeated vertex (random index triples!) have e01==e02 bitwise,
// and mul/mul/sub gives EXACT 0 (-> s=0 -> frag=1/8 everywhere, which
// dominates the loss), while fma contraction leaves a rounding residue ->
// s=+-1 -> face disappears -> loss shifts by ~580. numpy ref never fuses.
__device__ __forceinline__ float cross2(float ax, float ay, float bx, float by) {
#pragma clang fp contract(off)
  return ax * by - ay * bx;
}

// One fused kernel: per-block prep (project verts, build per-face edge
// constants in LDS), per-wave silhouette partial product over a face chunk,
// LDS combine across waves, squared-error reduce, per-block sum to bsum.
// Block = 8x8 pixel tile, 8 waves; wave w owns faces [w*fpc,(w+1)*fpc).
// t_k(p) = px*A.x + py*A.y + A.z ; frag = 1/((1+2^t0)(1+2^t1)(1+2^t2)).
__global__ __launch_bounds__(512) void fused_kernel(
    const float* __restrict__ verts, const int* __restrict__ faces,
    const float* __restrict__ cam, const float* __restrict__ ref,
    float* __restrict__ bsum, int V, int F, int fpc) {
  __shared__ float s_verts[3 * VMAX];
  __shared__ float4 s_fd[FMAX * 4];   // [face][edge0..2, pad] : 64B stride
  __shared__ float s_part[NWAVE * 64];

  int tid = threadIdx.x;

  // --- stage verts to LDS ---
  for (int i = tid; i < 3 * V; i += 512) s_verts[i] = verts[i];
  __syncthreads();

  // --- camera basis (uniform per thread) ---
  float ex = cam[0], ey = cam[1], ez = cam[2];
  float zn = sqrtf(ex * ex + ey * ey + ez * ez) + EPSF;
  float zx = -ex / zn, zy = -ey / zn, zz = -ez / zn;
  float xn = sqrtf(zz * zz + zx * zx) + EPSF;
  float xx = zz / xn, xz = -zx / xn;             // xy = 0
  float yx = zy * xz;                            // cross(z,x), xy=0
  float yy = zz * xx - zx * xz;
  float yz = -zy * xx;

  // --- per-face edge constants into LDS ---
  for (int f = tid; f < F; f += 512) {
    float pxs[3], pys[3];
#pragma unroll
    for (int k = 0; k < 3; ++k) {
      int vi = faces[3 * f + k];
      float ax = s_verts[3 * vi + 0] - ex;
      float ay = s_verts[3 * vi + 1] - ey;
      float az = s_verts[3 * vi + 2] - ez;
      float vx = ax * xx + az * xz;
      float vy = ax * yx + ay * yy + az * yz;
      float vz = ax * zx + ay * zy + az * zz;
      float zw = vz * TANV;
      pxs[k] = vx / zw;
      pys[k] = vy / zw;
    }
    float e01x = pxs[1] - pxs[0], e01y = pys[1] - pys[0];
    float e02x = pxs[2] - pxs[0], e02y = pys[2] - pys[0];
    float area = cross2(e01x, e01y, e02x, e02y);   // contraction-proof
    float s = (area > 0.0f) ? 1.0f : ((area < 0.0f) ? -1.0f : 0.0f);
    float K = -s * SIGMA_INV * LOG2E;
#pragma unroll
    for (int k = 0; k < 3; ++k) {
      int kn = (k == 2) ? 0 : k + 1;
      float dx = pxs[kn] - pxs[k], dy = pys[kn] - pys[k];
      float ln = sqrtf(dx * dx + dy * dy) + EPSF;
      float nx = -dy / ln, ny = dx / ln;
      float c = pxs[k] * nx + pys[k] * ny;
      s_fd[f * 4 + k] = make_float4(nx * K, ny * K, -c * K, 0.0f);
    }
  }
  __syncthreads();

  // --- silhouette: wave = face chunk, block = 8x8 pixels ---
  int lane = tid & 63, w = tid >> 6;
  int bx = blockIdx.x & 31, by = blockIdx.x >> 5;
  int ix = (bx << 3) + (lane & 7);
  int iy = (by << 3) + (lane >> 3);
  float px = (2.0f * (float)ix + 1.0f) * (1.0f / IMG) - 1.0f;
  float py = 1.0f - (2.0f * (float)iy + 1.0f) * (1.0f / IMG);
  float cx = ((float)(16 * bx + 8)) * (1.0f / IMG) - 1.0f;
  float cy = 1.0f - ((float)(16 * by + 8)) * (1.0f / IMG);
  const float h = 7.0f / IMG;                    // tile half-extent (centers)

  int f0 = w * fpc;
  int f1 = f0 + fpc; if (f1 > F) f1 = F;

  float acc = 1.0f;
  for (int base = f0; base < f1; base += 64) {
    int f = base + lane;
    int idx = f < F ? f : F - 1;
    float4 a0 = s_fd[idx * 4 + 0];
    float4 a1 = s_fd[idx * 4 + 1];
    float4 a2 = s_fd[idx * 4 + 2];
    // conservative min over tile of t_k; skip face iff some edge >= TSKIP
    float m0 = fmaf(cx, a0.x, fmaf(cy, a0.y, a0.z)) - (fabsf(a0.x) + fabsf(a0.y)) * h;
    float m1 = fmaf(cx, a1.x, fmaf(cy, a1.y, a1.z)) - (fabsf(a1.x) + fabsf(a1.y)) * h;
    float m2 = fmaf(cx, a2.x, fmaf(cy, a2.y, a2.z)) - (fabsf(a2.x) + fabsf(a2.y)) * h;
    bool rel = (f < f1) && (fmaxf(m0, fmaxf(m1, m2)) < TSKIP);
    unsigned long long mask = __ballot(rel ? 1 : 0);
    while (mask) {
      int j = __builtin_ctzll(mask);
      mask &= mask - 1;
      // broadcast face j's 9 constants from lane j's registers (no memory)
      float b0x = rlane(a0.x, j), b0y = rlane(a0.y, j), b0z = rlane(a0.z, j);
      float b1x = rlane(a1.x, j), b1y = rlane(a1.y, j), b1z = rlane(a1.z, j);
      float b2x = rlane(a2.x, j), b2y = rlane(a2.y, j), b2z = rlane(a2.z, j);
      float t0 = fmaf(px, b0x, fmaf(py, b0y, b0z));
      float t1 = fmaf(px, b1x, fmaf(py, b1y, b1z));
      float t2 = fmaf(px, b2x, fmaf(py, b2y, b2z));
      float D = (1.0f + fexp2(t0)) * (1.0f + fexp2(t1)) * (1.0f + fexp2(t2));
      acc *= 1.0f - frcp(D);
    }
  }

  s_part[w * 64 + lane] = acc;
  __syncthreads();

  if (w == 0) {
    float p = 1.0f;
#pragma unroll
    for (int c = 0; c < NWAVE; ++c) p *= s_part[c * 64 + lane];
    float sil = 1.0f - p;
    float d = sil - ref[iy * IMG + ix];
    float v = d * d;
#pragma unroll
    for (int off = 32; off > 0; off >>= 1) v += __shfl_down(v, off);
    if (lane == 0) bsum[blockIdx.x] = v;
  }
}

// Reduce 1024 block sums -> out[0]. Plain store (workspace is poisoned, but
// we overwrite; no memset dispatch needed).
__global__ __launch_bounds__(256) void reduce_kernel(const float* __restrict__ bsum,
                                                     float* __restrict__ out) {
  int tid = threadIdx.x;
  float v = 0.0f;
  for (int i = tid; i < NBLK; i += 256) v += bsum[i];
#pragma unroll
  for (int off = 32; off > 0; off >>= 1) v += __shfl_down(v, off);
  __shared__ float red[4];
  if ((tid & 63) == 0) red[tid >> 6] = v;
  __syncthreads();
  if (tid == 0) out[0] = red[0] + red[1] + red[2] + red[3];
}

extern "C" void kernel_launch(void* const* d_in, const int* in_sizes, int n_in,
                              void* d_out, int out_size, void* d_ws, size_t ws_size,
                              hipStream_t stream) {
  const float* verts = (const float*)d_in[0];
  const int* faces = (const int*)d_in[1];
  const float* cam = (const float*)d_in[2];
  const float* imref = (const float*)d_in[3];
  int V = in_sizes[0] / 3;  // 502
  int F = in_sizes[1] / 3;  // 1000
  float* out = (float*)d_out;
  float* bsum = (float*)d_ws;   // NBLK floats

  int fpc = (F + NWAVE - 1) / NWAVE;
  fused_kernel<<<NBLK, 512, 0, stream>>>(verts, faces, cam, imref, bsum,
                                         V, F, fpc);
  reduce_kernel<<<1, 256, 0, stream>>>(bsum, out);
}

// Round 6
// 89.161 us; speedup vs baseline: 1.5433x; 1.1757x over previous
//
#include <hip/hip_runtime.h>
#include <math.h>

#define IMG 256
#define NPIX (IMG*IMG)
#define SIGMA_INV 100.0f
#define EPSF 1e-6f
#define LOG2E 1.4426950408889634f
#define TANV 0.5773502691896258f   // tan(30 deg)
#define TSKIP 24.0f
#define FMAX 1024                  // F = 1000
#define NWAVE 8
#define NBLK (NPIX/64)             // 1024 blocks, one 8x8 tile each

__device__ __forceinline__ float fexp2(float x) {
#if __has_builtin(__builtin_amdgcn_exp2f)
  return __builtin_amdgcn_exp2f(x);
#else
  return exp2f(x);
#endif
}
__device__ __forceinline__ float frcp(float x) {
#if __has_builtin(__builtin_amdgcn_rcpf)
  return __builtin_amdgcn_rcpf(x);
#else
  return 1.0f / x;
#endif
}
__device__ __forceinline__ float rlane(float x, int j) {
#if __has_builtin(__builtin_amdgcn_readlane)
  return __int_as_float(__builtin_amdgcn_readlane(__float_as_int(x), j));
#else
  return __shfl(x, j);
#endif
}

// Contraction-off cross product (secondary protection for sign(area) of
// non-degenerate faces; the primary degenerate case is handled by an
// explicit index test below -- see R5 post-mortem: (a,b,b)-type repeated
// faces lost exact-zero area when prep was restructured).
__device__ __forceinline__ float cross2(float ax, float ay, float bx, float by) {
#pragma clang fp contract(off)
  return ax * by - ay * bx;
}

// Prep: one thread per face. Project 3 verts, emit edge constants (SoA):
// t_k(p) = px*A.x + py*A.y + A.z ; frag = 1/((1+2^t0)(1+2^t1)(1+2^t2)).
// Faces with a repeated vertex INDEX get s=0 exactly (numpy: bitwise-equal
// gathered rows -> mul/mul/sub -> exact 0 -> sign=0 -> frag=1/8 everywhere;
// these ~6 faces dominate the loss, so this must be bit-robust).
__global__ void prep_kernel(const float* __restrict__ verts,
                            const int* __restrict__ faces,
                            const float* __restrict__ cam,
                            float4* __restrict__ fd0, float4* __restrict__ fd1,
                            float4* __restrict__ fd2, int F) {
  int f = blockIdx.x * blockDim.x + threadIdx.x;
  if (f >= F) return;
  float ex = cam[0], ey = cam[1], ez = cam[2];
  float zn = sqrtf(ex * ex + ey * ey + ez * ez) + EPSF;
  float izn = frcp(zn);
  float zx = -ex * izn, zy = -ey * izn, zz = -ez * izn;
  float xn = sqrtf(zz * zz + zx * zx) + EPSF;
  float ixn = frcp(xn);
  float xx = zz * ixn, xz = -zx * ixn;           // xy = 0
  float yx = zy * xz;                            // cross(z,x) with xy=0
  float yy = zz * xx - zx * xz;
  float yz = -zy * xx;

  int i0 = faces[3 * f + 0], i1 = faces[3 * f + 1], i2 = faces[3 * f + 2];
  bool deg = (i0 == i1) | (i1 == i2) | (i0 == i2);
  int vi_[3] = {i0, i1, i2};

  float pxs[3], pys[3];
#pragma unroll
  for (int k = 0; k < 3; ++k) {
    int vi = vi_[k];
    float ax = verts[3 * vi + 0] - ex;
    float ay = verts[3 * vi + 1] - ey;
    float az = verts[3 * vi + 2] - ez;
    float vx = ax * xx + az * xz;
    float vy = ax * yx + ay * yy + az * yz;
    float vz = ax * zx + ay * zy + az * zz;
    float izw = frcp(vz * TANV);
    pxs[k] = vx * izw;
    pys[k] = vy * izw;
  }
  float e01x = pxs[1] - pxs[0], e01y = pys[1] - pys[0];
  float e02x = pxs[2] - pxs[0], e02y = pys[2] - pys[0];
  float area = cross2(e01x, e01y, e02x, e02y);
  float s = deg ? 0.0f
                : ((area > 0.0f) ? 1.0f : ((area < 0.0f) ? -1.0f : 0.0f));
  float K = -s * SIGMA_INV * LOG2E;
  float4 o[3];
#pragma unroll
  for (int k = 0; k < 3; ++k) {
    int kn = (k == 2) ? 0 : k + 1;
    float dx = pxs[kn] - pxs[k], dy = pys[kn] - pys[k];
    float il = frcp(sqrtf(dx * dx + dy * dy) + EPSF);
    float nx = -dy * il, ny = dx * il;
    float c = pxs[k] * nx + pys[k] * ny;
    o[k] = make_float4(nx * K, ny * K, -c * K, 0.0f);
  }
  fd0[f] = o[0]; fd1[f] = o[1]; fd2[f] = o[2];
}

// Silhouette + loss partial. Block = one 8x8 pixel tile, 8 waves; wave w owns
// faces [w*fpc,(w+1)*fpc). Phase 1: lane-parallel relevance scan (coalesced
// SoA global loads, L2-hot). Phase 2: uniform bit-loop; face constants
// broadcast from the scanning lane's registers via v_readlane -- no memory.
// 1024 blocks x 8 waves = 8192 waves = exactly full-GPU residency.
__global__ __launch_bounds__(512) void sil_kernel(
    const float4* __restrict__ fd0, const float4* __restrict__ fd1,
    const float4* __restrict__ fd2, const float* __restrict__ ref,
    float* __restrict__ bsum, int F, int fpc) {
  __shared__ float s_part[NWAVE * 64];

  int tid = threadIdx.x;
  int lane = tid & 63, w = tid >> 6;
  int bx = blockIdx.x & 31, by = blockIdx.x >> 5;
  int ix = (bx << 3) + (lane & 7);
  int iy = (by << 3) + (lane >> 3);
  float px = (2.0f * (float)ix + 1.0f) * (1.0f / IMG) - 1.0f;
  float py = 1.0f - (2.0f * (float)iy + 1.0f) * (1.0f / IMG);
  float cx = ((float)(16 * bx + 8)) * (1.0f / IMG) - 1.0f;
  float cy = 1.0f - ((float)(16 * by + 8)) * (1.0f / IMG);
  const float h = 7.0f / IMG;                    // tile half-extent (centers)

  int f0 = w * fpc;
  int f1 = f0 + fpc; if (f1 > F) f1 = F;

  float acc = 1.0f;
  for (int base = f0; base < f1; base += 64) {
    int f = base + lane;
    int idx = f < F ? f : F - 1;
    float4 a0 = fd0[idx];
    float4 a1 = fd1[idx];
    float4 a2 = fd2[idx];
    // conservative min over tile of t_k; skip face iff some edge >= TSKIP
    float m0 = fmaf(cx, a0.x, fmaf(cy, a0.y, a0.z)) - (fabsf(a0.x) + fabsf(a0.y)) * h;
    float m1 = fmaf(cx, a1.x, fmaf(cy, a1.y, a1.z)) - (fabsf(a1.x) + fabsf(a1.y)) * h;
    float m2 = fmaf(cx, a2.x, fmaf(cy, a2.y, a2.z)) - (fabsf(a2.x) + fabsf(a2.y)) * h;
    bool rel = (f < f1) && (fmaxf(m0, fmaxf(m1, m2)) < TSKIP);
    unsigned long long mask = __ballot(rel ? 1 : 0);
    while (mask) {
      int j = __builtin_ctzll(mask);
      mask &= mask - 1;
      // broadcast face j's 9 constants from lane j's registers (no memory)
      float b0x = rlane(a0.x, j), b0y = rlane(a0.y, j), b0z = rlane(a0.z, j);
      float b1x = rlane(a1.x, j), b1y = rlane(a1.y, j), b1z = rlane(a1.z, j);
      float b2x = rlane(a2.x, j), b2y = rlane(a2.y, j), b2z = rlane(a2.z, j);
      float t0 = fmaf(px, b0x, fmaf(py, b0y, b0z));
      float t1 = fmaf(px, b1x, fmaf(py, b1y, b1z));
      float t2 = fmaf(px, b2x, fmaf(py, b2y, b2z));
      float D = (1.0f + fexp2(t0)) * (1.0f + fexp2(t1)) * (1.0f + fexp2(t2));
      acc = fmaf(-frcp(D), acc, acc);            // acc *= 1 - 1/D
    }
  }

  s_part[w * 64 + lane] = acc;
  __syncthreads();

  if (w == 0) {
    float p = 1.0f;
#pragma unroll
    for (int c = 0; c < NWAVE; ++c) p *= s_part[c * 64 + lane];
    float sil = 1.0f - p;
    float d = sil - ref[iy * IMG + ix];
    float v = d * d;
#pragma unroll
    for (int off = 32; off > 0; off >>= 1) v += __shfl_down(v, off);
    if (lane == 0) bsum[blockIdx.x] = v;
  }
}

// Reduce 1024 block sums -> out[0].
__global__ __launch_bounds__(256) void reduce_kernel(const float* __restrict__ bsum,
                                                     float* __restrict__ out) {
  int tid = threadIdx.x;
  float v = 0.0f;
  for (int i = tid; i < NBLK; i += 256) v += bsum[i];
#pragma unroll
  for (int off = 32; off > 0; off >>= 1) v += __shfl_down(v, off);
  __shared__ float red[4];
  if ((tid & 63) == 0) red[tid >> 6] = v;
  __syncthreads();
  if (tid == 0) out[0] = red[0] + red[1] + red[2] + red[3];
}

extern "C" void kernel_launch(void* const* d_in, const int* in_sizes, int n_in,
                              void* d_out, int out_size, void* d_ws, size_t ws_size,
                              hipStream_t stream) {
  const float* verts = (const float*)d_in[0];
  const int* faces = (const int*)d_in[1];
  const float* cam = (const float*)d_in[2];
  const float* imref = (const float*)d_in[3];
  int V = in_sizes[0] / 3;  (void)V;
  int F = in_sizes[1] / 3;  // 1000
  float* out = (float*)d_out;

  char* ws = (char*)d_ws;
  float4* fd0 = (float4*)(ws + 0 * FMAX * 16);
  float4* fd1 = (float4*)(ws + 1 * FMAX * 16);
  float4* fd2 = (float4*)(ws + 2 * FMAX * 16);
  float* bsum = (float*)(ws + 3 * FMAX * 16);   // NBLK floats

  prep_kernel<<<(F + 255) / 256, 256, 0, stream>>>(verts, faces, cam,
                                                   fd0, fd1, fd2, F);
  int fpc = (F + NWAVE - 1) / NWAVE;
  sil_kernel<<<NBLK, 512, 0, stream>>>(fd0, fd1, fd2, imref, bsum, F, fpc);
  reduce_kernel<<<1, 256, 0, stream>>>(bsum, out);
}

// Round 7
// 84.802 us; speedup vs baseline: 1.6226x; 1.0514x over previous
//
#include <hip/hip_runtime.h>
#include <math.h>

#define IMG 256
#define NPIX (IMG*IMG)
#define SIGMA_INV 100.0f
#define EPSF 1e-6f
#define LOG2E 1.4426950408889634f
#define TANV 0.5773502691896258f   // tan(30 deg)
#define TSKIP 24.0f
#define FMAX 1024                  // F = 1000
#define NWAVE 8
#define NTILE 1024                 // 32x32 tiles of 8x8 px
#define NCHUNK 4
#define NSBLK (NTILE*NCHUNK)       // 4096 sil blocks
#define NLBLK 128                  // loss blocks (128*512 = NPIX)

__device__ __forceinline__ float fexp2(float x) {
#if __has_builtin(__builtin_amdgcn_exp2f)
  return __builtin_amdgcn_exp2f(x);
#else
  return exp2f(x);
#endif
}
__device__ __forceinline__ float frcp(float x) {
#if __has_builtin(__builtin_amdgcn_rcpf)
  return __builtin_amdgcn_rcpf(x);
#else
  return 1.0f / x;
#endif
}
__device__ __forceinline__ float rlane(float x, int j) {
#if __has_builtin(__builtin_amdgcn_readlane)
  return __int_as_float(__builtin_amdgcn_readlane(__float_as_int(x), j));
#else
  return __shfl(x, j);
#endif
}

// Contraction-off cross product (sign(area) of non-degenerate faces).
__device__ __forceinline__ float cross2(float ax, float ay, float bx, float by) {
#pragma clang fp contract(off)
  return ax * by - ay * bx;
}

// Prep: one thread per face. Project 3 verts, emit edge constants (SoA):
// t_k(p) = px*A.x + py*A.y + A.z ; frag = 1/((1+2^t0)(1+2^t1)(1+2^t2)).
// Faces with a repeated vertex INDEX get s=0 exactly (matches numpy: gather
// of identical rows -> exact-zero area -> sign=0 -> frag=1/8 everywhere;
// these ~6 faces dominate the loss, so this must be bit-robust).
__global__ void prep_kernel(const float* __restrict__ verts,
                            const int* __restrict__ faces,
                            const float* __restrict__ cam,
                            float4* __restrict__ fd0, float4* __restrict__ fd1,
                            float4* __restrict__ fd2, int F) {
  int f = blockIdx.x * blockDim.x + threadIdx.x;
  if (f >= F) return;
  float ex = cam[0], ey = cam[1], ez = cam[2];
  float zn = sqrtf(ex * ex + ey * ey + ez * ez) + EPSF;
  float izn = frcp(zn);
  float zx = -ex * izn, zy = -ey * izn, zz = -ez * izn;
  float xn = sqrtf(zz * zz + zx * zx) + EPSF;
  float ixn = frcp(xn);
  float xx = zz * ixn, xz = -zx * ixn;           // xy = 0
  float yx = zy * xz;                            // cross(z,x) with xy=0
  float yy = zz * xx - zx * xz;
  float yz = -zy * xx;

  int i0 = faces[3 * f + 0], i1 = faces[3 * f + 1], i2 = faces[3 * f + 2];
  bool deg = (i0 == i1) | (i1 == i2) | (i0 == i2);
  int vi_[3] = {i0, i1, i2};

  float pxs[3], pys[3];
#pragma unroll
  for (int k = 0; k < 3; ++k) {
    int vi = vi_[k];
    float ax = verts[3 * vi + 0] - ex;
    float ay = verts[3 * vi + 1] - ey;
    float az = verts[3 * vi + 2] - ez;
    float vx = ax * xx + az * xz;
    float vy = ax * yx + ay * yy + az * yz;
    float vz = ax * zx + ay * zy + az * zz;
    float izw = frcp(vz * TANV);
    pxs[k] = vx * izw;
    pys[k] = vy * izw;
  }
  float e01x = pxs[1] - pxs[0], e01y = pys[1] - pys[0];
  float e02x = pxs[2] - pxs[0], e02y = pys[2] - pys[0];
  float area = cross2(e01x, e01y, e02x, e02y);
  float s = deg ? 0.0f
                : ((area > 0.0f) ? 1.0f : ((area < 0.0f) ? -1.0f : 0.0f));
  float K = -s * SIGMA_INV * LOG2E;
  float4 o[3];
#pragma unroll
  for (int k = 0; k < 3; ++k) {
    int kn = (k == 2) ? 0 : k + 1;
    float dx = pxs[kn] - pxs[k], dy = pys[kn] - pys[k];
    float il = frcp(sqrtf(dx * dx + dy * dy) + EPSF);
    float nx = -dy * il, ny = dx * il;
    float c = pxs[k] * nx + pys[k] * ny;
    o[k] = make_float4(nx * K, ny * K, -c * K, 0.0f);
  }
  fd0[f] = o[0]; fd1[f] = o[1]; fd2[f] = o[2];
}

// Silhouette partial product. Block = (tile, face-chunk) decoded from a
// SWIZZLED blockIdx (odd multiplier mod 4096): hot tiles are contiguous in
// tile id (blob center), swizzle spreads them over dispatch order -> CUs.
// 8 waves split the chunk's 250 faces (<=32 bit-loop iters/wave): the
// bit-loop is issue-bound (~56 cyc/face/wave), so balance is everything.
// Phase 1: lane-parallel relevance scan (coalesced SoA loads, L2-hot).
// Phase 2: uniform bit-loop; constants broadcast via v_readlane (no memory).
__global__ __launch_bounds__(512) void sil_kernel(
    const float4* __restrict__ fd0, const float4* __restrict__ fd1,
    const float4* __restrict__ fd2, float* __restrict__ part,
    int F, int cpf, int fpw) {
  __shared__ float s_part[NWAVE * 64];

  int q = (blockIdx.x * 1021) & (NSBLK - 1);   // odd mult: bijection mod 4096
  int tile = q >> 2, chunk = q & 3;
  int tid = threadIdx.x;
  int lane = tid & 63, w = tid >> 6;
  int bx = tile & 31, by = tile >> 5;
  int ix = (bx << 3) + (lane & 7);
  int iy = (by << 3) + (lane >> 3);
  float px = (2.0f * (float)ix + 1.0f) * (1.0f / IMG) - 1.0f;
  float py = 1.0f - (2.0f * (float)iy + 1.0f) * (1.0f / IMG);
  float cx = ((float)(16 * bx + 8)) * (1.0f / IMG) - 1.0f;
  float cy = 1.0f - ((float)(16 * by + 8)) * (1.0f / IMG);
  const float h = 7.0f / IMG;                  // tile half-extent (centers)

  int c0 = chunk * cpf;
  int cF = c0 + cpf; if (cF > F) cF = F;
  int f0 = c0 + w * fpw;
  int f1 = f0 + fpw; if (f1 > cF) f1 = cF;

  float acc = 1.0f;
  for (int base = f0; base < f1; base += 64) {
    int f = base + lane;
    int idx = f < F ? f : F - 1;
    float4 a0 = fd0[idx];
    float4 a1 = fd1[idx];
    float4 a2 = fd2[idx];
    // conservative min over tile of t_k; skip face iff some edge >= TSKIP
    float m0 = fmaf(cx, a0.x, fmaf(cy, a0.y, a0.z)) - (fabsf(a0.x) + fabsf(a0.y)) * h;
    float m1 = fmaf(cx, a1.x, fmaf(cy, a1.y, a1.z)) - (fabsf(a1.x) + fabsf(a1.y)) * h;
    float m2 = fmaf(cx, a2.x, fmaf(cy, a2.y, a2.z)) - (fabsf(a2.x) + fabsf(a2.y)) * h;
    bool rel = (f < f1) && (fmaxf(m0, fmaxf(m1, m2)) < TSKIP);
    unsigned long long mask = __ballot(rel ? 1 : 0);
    while (mask) {
      int j = __builtin_ctzll(mask);
      mask &= mask - 1;
      // broadcast face j's 9 constants from lane j's registers (no memory)
      float b0x = rlane(a0.x, j), b0y = rlane(a0.y, j), b0z = rlane(a0.z, j);
      float b1x = rlane(a1.x, j), b1y = rlane(a1.y, j), b1z = rlane(a1.z, j);
      float b2x = rlane(a2.x, j), b2y = rlane(a2.y, j), b2z = rlane(a2.z, j);
      float t0 = fmaf(px, b0x, fmaf(py, b0y, b0z));
      float t1 = fmaf(px, b1x, fmaf(py, b1y, b1z));
      float t2 = fmaf(px, b2x, fmaf(py, b2y, b2z));
      float D = (1.0f + fexp2(t0)) * (1.0f + fexp2(t1)) * (1.0f + fexp2(t2));
      acc = fmaf(-frcp(D), acc, acc);            // acc *= 1 - 1/D
    }
  }

  s_part[w * 64 + lane] = acc;
  __syncthreads();

  if (w == 0) {
    float p = 1.0f;
#pragma unroll
    for (int c = 0; c < NWAVE; ++c) p *= s_part[c * 64 + lane];
    part[chunk * NPIX + iy * IMG + ix] = p;
  }
}

// Combine chunk partials, squared error vs ref, block-reduce to bsum.
__global__ __launch_bounds__(512) void loss_kernel(const float* __restrict__ part,
                                                   const float* __restrict__ ref,
                                                   float* __restrict__ bsum) {
  int p = blockIdx.x * 512 + threadIdx.x;
  float a = part[p] * part[p + NPIX] * part[p + 2 * NPIX] * part[p + 3 * NPIX];
  float d = (1.0f - a) - ref[p];
  float v = d * d;
#pragma unroll
  for (int off = 32; off > 0; off >>= 1) v += __shfl_down(v, off);
  __shared__ float red[8];
  if ((threadIdx.x & 63) == 0) red[threadIdx.x >> 6] = v;
  __syncthreads();
  if (threadIdx.x == 0) {
    float t = 0.0f;
#pragma unroll
    for (int c = 0; c < 8; ++c) t += red[c];
    bsum[blockIdx.x] = t;
  }
}

// Reduce NLBLK block sums -> out[0].
__global__ __launch_bounds__(128) void reduce_kernel(const float* __restrict__ bsum,
                                                     float* __restrict__ out) {
  int tid = threadIdx.x;
  float v = (tid < NLBLK) ? bsum[tid] : 0.0f;
#pragma unroll
  for (int off = 32; off > 0; off >>= 1) v += __shfl_down(v, off);
  __shared__ float red[2];
  if ((tid & 63) == 0) red[tid >> 6] = v;
  __syncthreads();
  if (tid == 0) out[0] = red[0] + red[1];
}

extern "C" void kernel_launch(void* const* d_in, const int* in_sizes, int n_in,
                              void* d_out, int out_size, void* d_ws, size_t ws_size,
                              hipStream_t stream) {
  const float* verts = (const float*)d_in[0];
  const int* faces = (const int*)d_in[1];
  const float* cam = (const float*)d_in[2];
  const float* imref = (const float*)d_in[3];
  int V = in_sizes[0] / 3;  (void)V;
  int F = in_sizes[1] / 3;  // 1000
  float* out = (float*)d_out;

  char* ws = (char*)d_ws;
  float4* fd0 = (float4*)(ws + 0 * FMAX * 16);
  float4* fd1 = (float4*)(ws + 1 * FMAX * 16);
  float4* fd2 = (float4*)(ws + 2 * FMAX * 16);
  float* part = (float*)(ws + 65536);                    // NCHUNK*NPIX floats
  float* bsum = (float*)(ws + 65536 + NCHUNK * NPIX * 4);  // NLBLK floats

  prep_kernel<<<(F + 255) / 256, 256, 0, stream>>>(verts, faces, cam,
                                                   fd0, fd1, fd2, F);
  int cpf = (F + NCHUNK - 1) / NCHUNK;   // faces per chunk (250)
  int fpw = (cpf + NWAVE - 1) / NWAVE;   // faces per wave  (32)
  sil_kernel<<<NSBLK, 512, 0, stream>>>(fd0, fd1, fd2, part, F, cpf, fpw);
  loss_kernel<<<NLBLK, 512, 0, stream>>>(part, imref, bsum);
  reduce_kernel<<<1, 128, 0, stream>>>(bsum, out);
}